// Round 5
// baseline (361.271 us; speedup 1.0000x reference)
//
#include <hip/hip_runtime.h>
#include <cstdint>

// ---------------------------------------------------------------------------
// T-LSTM cell, fp32 in/out, 3-pass split-bf16 MFMA.
// Round 5: A-operands loaded DIRECT global->VGPR (NT layout matches fragment
// layout; no LDS, no barrier dep). Only B staged in LDS, BK=64 (half the
// barriers), 32x32x16 MFMA (R2-verified layouts), row&7 XOR swizzle for
// 128B rows. 2 dispatches: prep(+transpose), mega.
// ---------------------------------------------------------------------------

typedef __attribute__((ext_vector_type(8))) __bf16 bf16x8;
typedef __attribute__((ext_vector_type(16))) float f32x16;
typedef __attribute__((ext_vector_type(8))) unsigned short ushort8;

__device__ __forceinline__ unsigned short f2bf_rn(float f) {
  unsigned int u = __float_as_uint(f);
  unsigned int r = u + 0x7fffu + ((u >> 16) & 1u);
  return (unsigned short)(r >> 16);
}
__device__ __forceinline__ float bf2f(unsigned short h) {
  return __uint_as_float(((unsigned int)h) << 16);
}
__device__ __forceinline__ float sigm_f(float x) {
  return 1.0f / (1.0f + __expf(-x));
}
__device__ __forceinline__ float tanh_f(float x) {
  return 1.0f - 2.0f / (__expf(2.0f * x) + 1.0f);
}
__device__ __forceinline__ void gl_lds16(const void* g, void* l) {
  __builtin_amdgcn_global_load_lds(
      (const __attribute__((address_space(1))) void*)g,
      (__attribute__((address_space(3))) void*)l, 16, 0, 0);
}

// split 16 consecutive fp32 -> 16 bf16 hi + 16 bf16 lo (16B stores)
__device__ __forceinline__ void cvt16(const float* __restrict__ s,
                                      unsigned short* __restrict__ hi,
                                      unsigned short* __restrict__ lo) {
  float4 v[4];
#pragma unroll
  for (int i = 0; i < 4; ++i) v[i] = ((const float4*)s)[i];
  const float* f = (const float*)v;
  ushort8 h[2], l[2];
#pragma unroll
  for (int i = 0; i < 16; ++i) {
    unsigned short hh = f2bf_rn(f[i]);
    ((unsigned short*)h)[i] = hh;
    ((unsigned short*)l)[i] = f2bf_rn(f[i] - bf2f(hh));
  }
  ((ushort8*)hi)[0] = h[0];
  ((ushort8*)hi)[1] = h[1];
  ((ushort8*)lo)[0] = l[0];
  ((ushort8*)lo)[1] = l[1];
}

// --- prep: all splits + W_decomp transpose in ONE dispatch.
// blocks [0,1536):    X = [input|hx], 16 elems/thread
// blocks [1536,3072): W = [w_ih|w_hh], rows gate-interleaved
// blocks [3072,4096): cx
// blocks [4096,4352): W_decomp transpose-split (64x64 tiles)
__global__ __launch_bounds__(256) void prep_k(
    const float* __restrict__ input, const float* __restrict__ hx,
    const float* __restrict__ w_ih, const float* __restrict__ w_hh,
    const float* __restrict__ cx, const float* __restrict__ Wd,
    unsigned short* __restrict__ Xhi, unsigned short* __restrict__ Xlo,
    unsigned short* __restrict__ Whi, unsigned short* __restrict__ Wlo,
    unsigned short* __restrict__ Chi, unsigned short* __restrict__ Clo,
    unsigned short* __restrict__ Dhi, unsigned short* __restrict__ Dlo) {
  const int bid = blockIdx.x;
  const int tid = threadIdx.x;
  if (bid < 1536) {
    const int u = bid * 256 + tid;
    const int row = u / 96;
    const int col = (u % 96) << 4;
    const float* src = (col < 512) ? (input + (long)row * 512 + col)
                                   : (hx + (long)row * 1024 + (col - 512));
    cvt16(src, Xhi + (long)row * 1536 + col, Xlo + (long)row * 1536 + col);
  } else if (bid < 3072) {
    const int u = (bid - 1536) * 256 + tid;
    const int n = u / 96;
    const int col = (u % 96) << 4;
    const int g = n >> 10;
    const int h = n & 1023;
    const long nd = ((h >> 5) << 7) | (g << 5) | (h & 31);
    const float* src = (col < 512) ? (w_ih + (long)n * 512 + col)
                                   : (w_hh + (long)n * 1024 + (col - 512));
    cvt16(src, Whi + nd * 1536 + col, Wlo + nd * 1536 + col);
  } else if (bid < 4096) {
    const int u = (bid - 3072) * 256 + tid;
    const int row = u >> 6;
    const int col = (u & 63) << 4;
    cvt16(cx + (long)row * 1024 + col, Chi + (long)row * 1024 + col,
          Clo + (long)row * 1024 + col);
  } else {
    __shared__ float tile[64][65];
    const int bid2 = bid - 4096;
    const int bx = (bid2 & 15) * 64;
    const int by = (bid2 >> 4) * 64;
    const int tx = tid & 63;
    const int ty = tid >> 6;
    for (int r = ty; r < 64; r += 4)
      tile[r][tx] = Wd[(long)(by + r) * 1024 + bx + tx];
    __syncthreads();
    for (int r = ty; r < 64; r += 4) {
      float v = tile[tx][r];  // = Wd[by+tx][bx+r]
      unsigned short h = f2bf_rn(v);
      long o = (long)(bx + r) * 1024 + by + tx;
      Dhi[o] = h;
      Dlo[o] = f2bf_rn(v - bf2f(h));
    }
  }
}

// --- mega kernel. Block = 128M x 128N; 4 waves stacked in M (32M x 128N each).
// 32x32x16 MFMA, 3-pass split-bf16.
// A fragments: direct global loads (lane lm=lane&31 -> row, lk=lane>>5 -> k-chunk).
// B: LDS, BK=64 (rows of 128 B = 8 chunks); phys chunk = logical ^ (row&7):
//   staging lane L (HW slot row r0+(L>>3), phys L&7) fetches logical
//   (L&7)^(L>>3); frag read of logical q at row r uses phys q^(r&7).
// phase 1: dacc = cx @ D^T (K=1024, B rows h0..h0+31)
// phase 2: acc[4] = X @ W'^T (K=1536, W' gate-interleaved: n-block j = gate j)
// epilogue: full T-LSTM pointwise -> hy, cy.
__global__ __launch_bounds__(256) void gemm_mega(
    const unsigned short* __restrict__ Xh, const unsigned short* __restrict__ Xl,
    const unsigned short* __restrict__ Wh, const unsigned short* __restrict__ Wl,
    const unsigned short* __restrict__ Ch, const unsigned short* __restrict__ Cl,
    const unsigned short* __restrict__ Dh, const unsigned short* __restrict__ Dl,
    const float* __restrict__ b_ih, const float* __restrict__ b_hh,
    const float* __restrict__ b_d, const float* __restrict__ cx,
    const float* __restrict__ t, float* __restrict__ out) {
  __shared__ __align__(16) unsigned short sBh[128 * 64];
  __shared__ __align__(16) unsigned short sBl[128 * 64];

  const int n_blk = blockIdx.x & 31;
  const int m_blk = blockIdx.x >> 5;
  const int m0 = m_blk * 128;
  const int n0 = n_blk * 128;  // interleaved-W row offset
  const int h0 = n_blk * 32;

  const int tid = threadIdx.x;
  const int wave = tid >> 6;
  const int lane = tid & 63;
  const int lm = lane & 31;
  const int lk = lane >> 5;
  const int lmw = lm & 7;
  // staging lane invariants
  const int sg = lane >> 3;              // subrow 0..7
  const int sq = (lane & 7) ^ sg;        // logical chunk to fetch

  // ---------------- phase 1: decomp ----------------
  f32x16 dacc;
#pragma unroll
  for (int r = 0; r < 16; ++r) dacc[r] = 0.f;
  {
    const long arow = (long)(m0 + wave * 32 + lm) * 1024 + lk * 8;
    const long brow = (long)(h0 + wave * 8 + sg) * 1024 + sq * 8;
    unsigned short* dsth = sBh + (wave * 8) * 64;
    unsigned short* dstl = sBl + (wave * 8) * 64;
    for (int kt = 0; kt < 1024; kt += 64) {
      bf16x8 ah[4], al[4];
#pragma unroll
      for (int kh = 0; kh < 4; ++kh) {
        ah[kh] = *(const bf16x8*)(Ch + arow + kt + kh * 16);
        al[kh] = *(const bf16x8*)(Cl + arow + kt + kh * 16);
      }
      gl_lds16(Dh + brow + kt, dsth);
      gl_lds16(Dl + brow + kt, dstl);
      __syncthreads();
#pragma unroll
      for (int kh = 0; kh < 4; ++kh) {
        const int pc = ((kh * 2 + lk) ^ lmw) << 3;
        bf16x8 bh = *(const bf16x8*)(sBh + lm * 64 + pc);
        bf16x8 bl = *(const bf16x8*)(sBl + lm * 64 + pc);
        dacc = __builtin_amdgcn_mfma_f32_32x32x16_bf16(ah[kh], bh, dacc, 0, 0, 0);
        dacc = __builtin_amdgcn_mfma_f32_32x32x16_bf16(ah[kh], bl, dacc, 0, 0, 0);
        dacc = __builtin_amdgcn_mfma_f32_32x32x16_bf16(al[kh], bh, dacc, 0, 0, 0);
      }
      __syncthreads();
    }
  }

  // ---------------- phase 2: gates ----------------
  f32x16 acc[4];
#pragma unroll
  for (int j = 0; j < 4; ++j)
#pragma unroll
    for (int r = 0; r < 16; ++r) acc[j][r] = 0.f;
  {
    const long arow = (long)(m0 + wave * 32 + lm) * 1536 + lk * 8;
    const long brow = (long)(n0 + wave * 32 + sg) * 1536 + sq * 8;
    for (int kt = 0; kt < 1536; kt += 64) {
      bf16x8 ah[4], al[4];
#pragma unroll
      for (int kh = 0; kh < 4; ++kh) {
        ah[kh] = *(const bf16x8*)(Xh + arow + kt + kh * 16);
        al[kh] = *(const bf16x8*)(Xl + arow + kt + kh * 16);
      }
#pragma unroll
      for (int i = 0; i < 4; ++i) {
        const long gb = brow + (long)i * 8 * 1536 + kt;
        const int loff = (wave * 32 + i * 8) * 64;
        gl_lds16(Wh + gb, sBh + loff);
        gl_lds16(Wl + gb, sBl + loff);
      }
      __syncthreads();
#pragma unroll
      for (int kh = 0; kh < 4; ++kh) {
        const int pc = ((kh * 2 + lk) ^ lmw) << 3;
        bf16x8 bh[4], bl[4];
#pragma unroll
        for (int nb = 0; nb < 4; ++nb) {
          bh[nb] = *(const bf16x8*)(sBh + (nb * 32 + lm) * 64 + pc);
          bl[nb] = *(const bf16x8*)(sBl + (nb * 32 + lm) * 64 + pc);
        }
#pragma unroll
        for (int nb = 0; nb < 4; ++nb) {
          acc[nb] = __builtin_amdgcn_mfma_f32_32x32x16_bf16(ah[kh], bh[nb], acc[nb], 0, 0, 0);
          acc[nb] = __builtin_amdgcn_mfma_f32_32x32x16_bf16(ah[kh], bl[nb], acc[nb], 0, 0, 0);
          acc[nb] = __builtin_amdgcn_mfma_f32_32x32x16_bf16(al[kh], bh[nb], acc[nb], 0, 0, 0);
        }
      }
      __syncthreads();
    }
  }

  // ---------------- epilogue ----------------
  // C/D 32x32 layout (R2-verified): col = lane&31, row = (reg&3)+8*(reg>>2)+4*lk
  const int h = h0 + lm;
  const float bsum_i = b_ih[h] + b_hh[h];
  const float bsum_f = b_ih[1024 + h] + b_hh[1024 + h];
  const float bsum_g = b_ih[2048 + h] + b_hh[2048 + h];
  const float bsum_o = b_ih[3072 + h] + b_hh[3072 + h];
  const float bd = b_d[h];
#pragma unroll
  for (int reg = 0; reg < 16; ++reg) {
    const int m = m0 + wave * 32 + (reg & 3) + 8 * (reg >> 2) + 4 * lk;
    const float tv = t[m];
    const float T = (tv != 0.0f) ? (1.0f / tv) : 0.0f;
    const float cst = tanh_f(dacc[reg] + bd);
    const float cadj = cx[(long)m * 1024 + h] + (T - 1.0f) * cst;
    const float ig = sigm_f(acc[0][reg] + bsum_i);
    const float fg = sigm_f(acc[1][reg] + bsum_f);
    const float cg = tanh_f(acc[2][reg] + bsum_g);
    const float og = sigm_f(acc[3][reg] + bsum_o);
    const float cy = fg * cadj + ig * cg;
    const float hy = og * tanh_f(cy);
    out[(long)m * 1024 + h] = hy;
    out[4096L * 1024 + (long)m * 1024 + h] = cy;
  }
}

extern "C" void kernel_launch(void* const* d_in, const int* in_sizes, int n_in,
                              void* d_out, int out_size, void* d_ws, size_t ws_size,
                              hipStream_t stream) {
  const float* input = (const float*)d_in[0];
  const float* t     = (const float*)d_in[1];
  const float* hx    = (const float*)d_in[2];
  const float* cx    = (const float*)d_in[3];
  const float* w_ih  = (const float*)d_in[4];
  const float* w_hh  = (const float*)d_in[5];
  const float* b_ih  = (const float*)d_in[6];
  const float* b_hh  = (const float*)d_in[7];
  const float* Wd    = (const float*)d_in[8];
  const float* b_d   = (const float*)d_in[9];

  const long B = 4096, H = 1024, KX = 1536, NG = 4096;

  char* ws = (char*)d_ws;
  unsigned short* Xhi = (unsigned short*)ws; ws += B * KX * 2;
  unsigned short* Xlo = (unsigned short*)ws; ws += B * KX * 2;
  unsigned short* Whi = (unsigned short*)ws; ws += NG * KX * 2;
  unsigned short* Wlo = (unsigned short*)ws; ws += NG * KX * 2;
  unsigned short* Chi = (unsigned short*)ws; ws += B * H * 2;
  unsigned short* Clo = (unsigned short*)ws; ws += B * H * 2;
  unsigned short* Dhi = (unsigned short*)ws; ws += H * H * 2;
  unsigned short* Dlo = (unsigned short*)ws; ws += H * H * 2;

  // 1: all splits + transpose, one dispatch
  prep_k<<<4352, 256, 0, stream>>>(input, hx, w_ih, w_hh, cx, Wd,
                                   Xhi, Xlo, Whi, Wlo, Chi, Clo, Dhi, Dlo);
  // 2: mega GEMM (decomp + gates + pointwise epilogue)
  gemm_mega<<<1024, 256, 0, stream>>>(Xhi, Xlo, Whi, Wlo, Chi, Clo, Dhi, Dlo,
                                      b_ih, b_hh, b_d, cx, t, (float*)d_out);
}

// Round 6
// 335.716 us; speedup vs baseline: 1.0761x; 1.0761x over previous
//
#include <hip/hip_runtime.h>
#include <cstdint>

// ---------------------------------------------------------------------------
// T-LSTM cell, fp32 in/out, 3-pass split-bf16 MFMA.
// Round 6: R4 structure (LDS-staged A and B, 16x16x32 MFMA, proven
// (r>>1)&3 swizzle = 0 conflicts) with BK=64 built as 2 independent BK=32
// subtiles -> half the barrier pairs, 96 MFMA between barriers. 64 KB LDS,
// still 2 blocks/CU (reg-bound). 2 dispatches: prep(+transpose), mega.
// ---------------------------------------------------------------------------

typedef __attribute__((ext_vector_type(8))) __bf16 bf16x8;
typedef __attribute__((ext_vector_type(4))) float f32x4;
typedef __attribute__((ext_vector_type(8))) unsigned short ushort8;

__device__ __forceinline__ unsigned short f2bf_rn(float f) {
  unsigned int u = __float_as_uint(f);
  unsigned int r = u + 0x7fffu + ((u >> 16) & 1u);
  return (unsigned short)(r >> 16);
}
__device__ __forceinline__ float bf2f(unsigned short h) {
  return __uint_as_float(((unsigned int)h) << 16);
}
__device__ __forceinline__ float sigm_f(float x) {
  return 1.0f / (1.0f + __expf(-x));
}
__device__ __forceinline__ float tanh_f(float x) {
  return 1.0f - 2.0f / (__expf(2.0f * x) + 1.0f);
}
__device__ __forceinline__ void gl_lds16(const void* g, void* l) {
  __builtin_amdgcn_global_load_lds(
      (const __attribute__((address_space(1))) void*)g,
      (__attribute__((address_space(3))) void*)l, 16, 0, 0);
}

// split 16 consecutive fp32 -> 16 bf16 hi + 16 bf16 lo (16B stores)
__device__ __forceinline__ void cvt16(const float* __restrict__ s,
                                      unsigned short* __restrict__ hi,
                                      unsigned short* __restrict__ lo) {
  float4 v[4];
#pragma unroll
  for (int i = 0; i < 4; ++i) v[i] = ((const float4*)s)[i];
  const float* f = (const float*)v;
  ushort8 h[2], l[2];
#pragma unroll
  for (int i = 0; i < 16; ++i) {
    unsigned short hh = f2bf_rn(f[i]);
    ((unsigned short*)h)[i] = hh;
    ((unsigned short*)l)[i] = f2bf_rn(f[i] - bf2f(hh));
  }
  ((ushort8*)hi)[0] = h[0];
  ((ushort8*)hi)[1] = h[1];
  ((ushort8*)lo)[0] = l[0];
  ((ushort8*)lo)[1] = l[1];
}

// --- prep: all splits + W_decomp transpose in ONE dispatch (R5-proven).
__global__ __launch_bounds__(256) void prep_k(
    const float* __restrict__ input, const float* __restrict__ hx,
    const float* __restrict__ w_ih, const float* __restrict__ w_hh,
    const float* __restrict__ cx, const float* __restrict__ Wd,
    unsigned short* __restrict__ Xhi, unsigned short* __restrict__ Xlo,
    unsigned short* __restrict__ Whi, unsigned short* __restrict__ Wlo,
    unsigned short* __restrict__ Chi, unsigned short* __restrict__ Clo,
    unsigned short* __restrict__ Dhi, unsigned short* __restrict__ Dlo) {
  const int bid = blockIdx.x;
  const int tid = threadIdx.x;
  if (bid < 1536) {
    const int u = bid * 256 + tid;
    const int row = u / 96;
    const int col = (u % 96) << 4;
    const float* src = (col < 512) ? (input + (long)row * 512 + col)
                                   : (hx + (long)row * 1024 + (col - 512));
    cvt16(src, Xhi + (long)row * 1536 + col, Xlo + (long)row * 1536 + col);
  } else if (bid < 3072) {
    const int u = (bid - 1536) * 256 + tid;
    const int n = u / 96;
    const int col = (u % 96) << 4;
    const int g = n >> 10;
    const int h = n & 1023;
    const long nd = ((h >> 5) << 7) | (g << 5) | (h & 31);  // gate-interleave
    const float* src = (col < 512) ? (w_ih + (long)n * 512 + col)
                                   : (w_hh + (long)n * 1024 + (col - 512));
    cvt16(src, Whi + nd * 1536 + col, Wlo + nd * 1536 + col);
  } else if (bid < 4096) {
    const int u = (bid - 3072) * 256 + tid;
    const int row = u >> 6;
    const int col = (u & 63) << 4;
    cvt16(cx + (long)row * 1024 + col, Chi + (long)row * 1024 + col,
          Clo + (long)row * 1024 + col);
  } else {
    __shared__ float tile[64][65];
    const int bid2 = bid - 4096;
    const int bx = (bid2 & 15) * 64;
    const int by = (bid2 >> 4) * 64;
    const int tx = tid & 63;
    const int ty = tid >> 6;
    for (int r = ty; r < 64; r += 4)
      tile[r][tx] = Wd[(long)(by + r) * 1024 + bx + tx];
    __syncthreads();
    for (int r = ty; r < 64; r += 4) {
      float v = tile[tx][r];  // = Wd[by+tx][bx+r]
      unsigned short h = f2bf_rn(v);
      long o = (long)(bx + r) * 1024 + by + tx;
      Dhi[o] = h;
      Dlo[o] = f2bf_rn(v - bf2f(h));
    }
  }
}

// --- mega kernel: per block (m_blk, n_blk):
//   phase 1: dacc[2][2] = cx[m-range128] @ D[h-range32]^T   (K=1024)
//   phase 2: acc[2][8]  = X[m-range128]  @ W'[n-range128]^T (K=1536)
//   epilogue: full T-LSTM pointwise -> hy, cy.
// 256 thr, 4 waves stacked in M (32Mx128N each). 16x16x32 MFMA.
// BK=64 = two BK=32 subtiles, each with R4's proven LDS geometry:
//   64-B rows; phys chunk p of row r holds logical p^((r>>1)&3); staging lane
//   L fetches logical (L&3)^((L>>3)&3). 0 bank conflicts (stride-8 groups see
//   only free 2-way aliasing). One barrier pair per 64 K (96 MFMA between).
__global__ __launch_bounds__(256) void gemm_mega(
    const unsigned short* __restrict__ Xh, const unsigned short* __restrict__ Xl,
    const unsigned short* __restrict__ Wh, const unsigned short* __restrict__ Wl,
    const unsigned short* __restrict__ Ch, const unsigned short* __restrict__ Cl,
    const unsigned short* __restrict__ Dh, const unsigned short* __restrict__ Dl,
    const float* __restrict__ b_ih, const float* __restrict__ b_hh,
    const float* __restrict__ b_d, const float* __restrict__ cx,
    const float* __restrict__ t, float* __restrict__ out) {
  __shared__ __align__(16) unsigned short sAh[2][128 * 32];
  __shared__ __align__(16) unsigned short sAl[2][128 * 32];
  __shared__ __align__(16) unsigned short sBh[2][128 * 32];
  __shared__ __align__(16) unsigned short sBl[2][128 * 32];

  const int n_blk = blockIdx.x & 31;
  const int m_blk = blockIdx.x >> 5;
  const int m0 = m_blk * 128;
  const int n0 = n_blk * 128;  // interleaved-W row offset
  const int h0 = n_blk * 32;

  const int tid = threadIdx.x;
  const int wave = tid >> 6;
  const int lane = tid & 63;
  const int srow = lane >> 2;
  const int ssw = (((lane & 3) ^ ((lane >> 3) & 3)) << 3);  // bf16 elems
  const int fm = lane & 15;
  const int fq = lane >> 4;
  const int psw = (fq ^ ((fm >> 1) & 3)) << 3;

  // ---------------- phase 1: decomp ----------------
  f32x4 dacc[2][2];
#pragma unroll
  for (int i = 0; i < 2; ++i)
#pragma unroll
    for (int j = 0; j < 2; ++j) dacc[i][j] = {0.f, 0.f, 0.f, 0.f};

  {
    // B staging: wave0/1 -> sBh rows 0-15/16-31; wave2/3 -> sBl same
    const unsigned short* dsrc = (wave < 2) ? Dh : Dl;
    const int drow = (wave & 1) * 16;
    const long dgbase = (long)(h0 + drow + srow) * 1024 + ssw;
    for (int kt = 0; kt < 1024; kt += 64) {
#pragma unroll
      for (int s = 0; s < 2; ++s) {
#pragma unroll
        for (int r = 0; r < 2; ++r) {
          const int rowb = r * 64 + wave * 16;
          const long gA = (long)(m0 + rowb + srow) * 1024 + kt + s * 32 + ssw;
          gl_lds16(Ch + gA, sAh[s] + rowb * 32);
          gl_lds16(Cl + gA, sAl[s] + rowb * 32);
        }
        unsigned short* ddst = ((wave < 2) ? sBh[s] : sBl[s]) + drow * 32;
        gl_lds16(dsrc + dgbase + kt + s * 32, ddst);
      }
      __syncthreads();
#pragma unroll
      for (int s = 0; s < 2; ++s) {
        bf16x8 ah[2], al[2], bh[2], bl[2];
#pragma unroll
        for (int i = 0; i < 2; ++i) {
          const int ao = (wave * 32 + i * 16 + fm) * 32 + psw;
          ah[i] = *(const bf16x8*)(sAh[s] + ao);
          al[i] = *(const bf16x8*)(sAl[s] + ao);
          const int bo = (i * 16 + fm) * 32 + psw;
          bh[i] = *(const bf16x8*)(sBh[s] + bo);
          bl[i] = *(const bf16x8*)(sBl[s] + bo);
        }
#pragma unroll
        for (int i = 0; i < 2; ++i)
#pragma unroll
          for (int j = 0; j < 2; ++j) {
            dacc[i][j] = __builtin_amdgcn_mfma_f32_16x16x32_bf16(ah[i], bh[j], dacc[i][j], 0, 0, 0);
            dacc[i][j] = __builtin_amdgcn_mfma_f32_16x16x32_bf16(ah[i], bl[j], dacc[i][j], 0, 0, 0);
            dacc[i][j] = __builtin_amdgcn_mfma_f32_16x16x32_bf16(al[i], bh[j], dacc[i][j], 0, 0, 0);
          }
      }
      __syncthreads();
    }
  }

  // ---------------- phase 2: gates ----------------
  f32x4 acc[2][8];
#pragma unroll
  for (int i = 0; i < 2; ++i)
#pragma unroll
    for (int j = 0; j < 8; ++j) acc[i][j] = {0.f, 0.f, 0.f, 0.f};

  for (int kt = 0; kt < 1536; kt += 64) {
#pragma unroll
    for (int s = 0; s < 2; ++s)
#pragma unroll
      for (int r = 0; r < 2; ++r) {
        const int rowb = r * 64 + wave * 16;
        const long gA = (long)(m0 + rowb + srow) * 1536 + kt + s * 32 + ssw;
        const long gB = (long)(n0 + rowb + srow) * 1536 + kt + s * 32 + ssw;
        gl_lds16(Xh + gA, sAh[s] + rowb * 32);
        gl_lds16(Xl + gA, sAl[s] + rowb * 32);
        gl_lds16(Wh + gB, sBh[s] + rowb * 32);
        gl_lds16(Wl + gB, sBl[s] + rowb * 32);
      }
    __syncthreads();
#pragma unroll
    for (int s = 0; s < 2; ++s) {
      bf16x8 ah[2], al[2];
#pragma unroll
      for (int i = 0; i < 2; ++i) {
        const int ao = (wave * 32 + i * 16 + fm) * 32 + psw;
        ah[i] = *(const bf16x8*)(sAh[s] + ao);
        al[i] = *(const bf16x8*)(sAl[s] + ao);
      }
#pragma unroll
      for (int jh = 0; jh < 2; ++jh) {
        bf16x8 bh[4], bl[4];
#pragma unroll
        for (int jj = 0; jj < 4; ++jj) {
          const int bo = ((jh * 4 + jj) * 16 + fm) * 32 + psw;
          bh[jj] = *(const bf16x8*)(sBh[s] + bo);
          bl[jj] = *(const bf16x8*)(sBl[s] + bo);
        }
#pragma unroll
        for (int i = 0; i < 2; ++i)
#pragma unroll
          for (int jj = 0; jj < 4; ++jj) {
            const int j = jh * 4 + jj;
            acc[i][j] = __builtin_amdgcn_mfma_f32_16x16x32_bf16(ah[i], bh[jj], acc[i][j], 0, 0, 0);
            acc[i][j] = __builtin_amdgcn_mfma_f32_16x16x32_bf16(ah[i], bl[jj], acc[i][j], 0, 0, 0);
            acc[i][j] = __builtin_amdgcn_mfma_f32_16x16x32_bf16(al[i], bh[jj], acc[i][j], 0, 0, 0);
          }
      }
    }
    __syncthreads();
  }

  // ---------------- epilogue ----------------
  // C/D 16x16 layout (m89-verified): col = lane&15, row = fq*4 + r
  // thread's outputs: m = m0 + wave*32 + i*16 + fq*4 + r ; h = h0 + j0*16 + fm
  // gate g value at acc[i][g*2+j0][r]
#pragma unroll
  for (int j0 = 0; j0 < 2; ++j0) {
    const int h = h0 + j0 * 16 + fm;
    const float bsum_i = b_ih[h] + b_hh[h];
    const float bsum_f = b_ih[1024 + h] + b_hh[1024 + h];
    const float bsum_g = b_ih[2048 + h] + b_hh[2048 + h];
    const float bsum_o = b_ih[3072 + h] + b_hh[3072 + h];
    const float bd = b_d[h];
#pragma unroll
    for (int i = 0; i < 2; ++i) {
#pragma unroll
      for (int r = 0; r < 4; ++r) {
        const int m = m0 + wave * 32 + i * 16 + fq * 4 + r;
        const float tv = t[m];
        const float T = (tv != 0.0f) ? (1.0f / tv) : 0.0f;
        const float cst = tanh_f(dacc[i][j0][r] + bd);
        const float cadj = cx[(long)m * 1024 + h] + (T - 1.0f) * cst;
        const float ig = sigm_f(acc[i][0 + j0][r] + bsum_i);
        const float fg = sigm_f(acc[i][2 + j0][r] + bsum_f);
        const float cg = tanh_f(acc[i][4 + j0][r] + bsum_g);
        const float og = sigm_f(acc[i][6 + j0][r] + bsum_o);
        const float cy = fg * cadj + ig * cg;
        const float hy = og * tanh_f(cy);
        out[(long)m * 1024 + h] = hy;
        out[4096L * 1024 + (long)m * 1024 + h] = cy;
      }
    }
  }
}

extern "C" void kernel_launch(void* const* d_in, const int* in_sizes, int n_in,
                              void* d_out, int out_size, void* d_ws, size_t ws_size,
                              hipStream_t stream) {
  const float* input = (const float*)d_in[0];
  const float* t     = (const float*)d_in[1];
  const float* hx    = (const float*)d_in[2];
  const float* cx    = (const float*)d_in[3];
  const float* w_ih  = (const float*)d_in[4];
  const float* w_hh  = (const float*)d_in[5];
  const float* b_ih  = (const float*)d_in[6];
  const float* b_hh  = (const float*)d_in[7];
  const float* Wd    = (const float*)d_in[8];
  const float* b_d   = (const float*)d_in[9];

  const long B = 4096, H = 1024, KX = 1536, NG = 4096;

  char* ws = (char*)d_ws;
  unsigned short* Xhi = (unsigned short*)ws; ws += B * KX * 2;
  unsigned short* Xlo = (unsigned short*)ws; ws += B * KX * 2;
  unsigned short* Whi = (unsigned short*)ws; ws += NG * KX * 2;
  unsigned short* Wlo = (unsigned short*)ws; ws += NG * KX * 2;
  unsigned short* Chi = (unsigned short*)ws; ws += B * H * 2;
  unsigned short* Clo = (unsigned short*)ws; ws += B * H * 2;
  unsigned short* Dhi = (unsigned short*)ws; ws += H * H * 2;
  unsigned short* Dlo = (unsigned short*)ws; ws += H * H * 2;

  // 1: all splits + transpose, one dispatch
  prep_k<<<4352, 256, 0, stream>>>(input, hx, w_ih, w_hh, cx, Wd,
                                   Xhi, Xlo, Whi, Wlo, Chi, Clo, Dhi, Dlo);
  // 2: mega GEMM (decomp + gates + pointwise epilogue)
  gemm_mega<<<1024, 256, 0, stream>>>(Xhi, Xlo, Whi, Wlo, Chi, Clo, Dhi, Dlo,
                                      b_ih, b_hh, b_d, cx, t, (float*)d_out);
}